// Round 2
// baseline (286.381 us; speedup 1.0000x reference)
//
#include <hip/hip_runtime.h>
#include <hip/hip_bf16.h>

typedef __attribute__((ext_vector_type(8))) short short8;
typedef __attribute__((ext_vector_type(16))) float floatx16;

#define Bn 32
#define Ln 512
#define Cn 300
#define Hn 512
#define Nn (Bn*Ln)          // 16384
#define XBP 518             // 512 + 3 halo each side
#define XBC 320             // channels padded to 10*32
#define HK 1216             // 1200 padded to 19*64
#define LDST 72             // LDS row stride in shorts: 36 words === 4 mod 32 -> conflict-free b128

// workspace layout in bf16 elements
#define XB_OFF 0
#define XB_ELEMS (Bn*XBP*XBC)           // 5,304,320
#define WB_OFF (XB_OFF + XB_ELEMS)
#define WB_ELEMS 1597440                 // 384*320*(1+2+3+7)
#define WC_OFF (WB_OFF + WB_ELEMS)
#define WC_ELEMS (Hn*HK)
#define HB_OFF (WC_OFF + WC_ELEMS)
#define HB_ELEMS (Nn*HK)

// ---------------- prep kernels ----------------

__global__ void prep_x(const float* __restrict__ x, __hip_bfloat16* __restrict__ xb) {
    int idx = blockIdx.x * 256 + threadIdx.x;
    if (idx >= Bn * XBP * XBC) return;
    int c = idx % XBC;
    int t = idx / XBC;
    int p = t % XBP;
    int b = t / XBP;
    int l = p - 3;
    l = l < 0 ? 0 : (l > Ln - 1 ? Ln - 1 : l);   // replication pad
    float v = (c < Cn) ? x[(b * Ln + l) * Cn + c] : 0.f;
    xb[idx] = __float2bfloat16(v);
}

// layout per conv: base + m*(taps*320) + tap*320 + c ; m in [0,384), c in [0,320)
__global__ void prep_w(const float* __restrict__ w1, const float* __restrict__ w2,
                       const float* __restrict__ w3, const float* __restrict__ w7,
                       __hip_bfloat16* __restrict__ Wb) {
    int idx = blockIdx.x * 256 + threadIdx.x;
    if (idx >= WB_ELEMS) return;
    int r = idx, taps; const float* w;
    if (r < 122880)       { taps = 1; w = w1; }
    else if (r < 368640)  { taps = 2; w = w2; r -= 122880; }
    else if (r < 737280)  { taps = 3; w = w3; r -= 368640; }
    else                  { taps = 7; w = w7; r -= 737280; }
    int per_m = taps * 320;
    int m   = r / per_m;
    int r2  = r % per_m;
    int tap = r2 / 320;
    int c   = r2 % 320;
    float v = (m < Cn && c < Cn) ? w[(m * Cn + c) * taps + tap] : 0.f;
    Wb[idx] = __float2bfloat16(v);
}

// combined linear weight: cols 0-599 = slp cols 0-599, 600-899 = col k + col k+300 (x3+x5),
// 900-1199 = col k+300 (x7), 1200-1215 = 0
__global__ void prep_wc(const float* __restrict__ slp_w, __hip_bfloat16* __restrict__ Wc) {
    int idx = blockIdx.x * 256 + threadIdx.x;
    if (idx >= Hn * HK) return;
    int k = idx % HK;
    int h = idx / HK;
    const float* row = slp_w + h * 1500;
    float v;
    if (k < 600)       v = row[k];
    else if (k < 900)  v = row[k] + row[k + 300];
    else if (k < 1200) v = row[k + 300];
    else               v = 0.f;
    Wc[idx] = __float2bfloat16(v);
}

#define MFMA __builtin_amdgcn_mfma_f32_32x32x16_bf16

// ---------------- conv GEMM ----------------
// grid (64 n-tiles of 256, 12 m-tiles; heavy convs first), block 256 = 4 waves
// block tile 256n x 128m; wave tile 128n x 64m (4x2 of 32x32x16); BK=64
__global__ __launch_bounds__(256, 2) void conv_kernel(
        const __hip_bfloat16* __restrict__ xbg, const __hip_bfloat16* __restrict__ Wbg,
        const float* __restrict__ bias1, const float* __restrict__ bias2,
        const float* __restrict__ bias3, const float* __restrict__ bias7,
        __hip_bfloat16* __restrict__ hbuf) {
    __shared__ __align__(16) short xs[262 * LDST];   // 37,728 B
    __shared__ __align__(16) short wl[128 * LDST];   // 18,432 B

    const int tid  = threadIdx.x;
    const int lane = tid & 63;
    const int wave = tid >> 6;
    const int wn = wave & 1, wm = wave >> 1;
    const int lr = lane & 31;
    const int lk = (lane >> 5) * 8;

    const int nt = blockIdx.x;
    const int my = blockIdx.y;
    const int cid = 3 - my / 3;              // heavy (k=7) first
    const int m0  = (my % 3) * 128;

    const int taps  = (cid == 0) ? 1 : (cid == 1) ? 2 : (cid == 2) ? 3 : 7;
    const int lead  = (cid == 2) ? 1 : (cid == 3) ? 3 : 0;
    const int wbase = (cid == 0) ? 0 : (cid == 1) ? 122880 : (cid == 2) ? 368640 : 737280;
    const int pm    = taps * 320;

    const int b  = nt >> 1;
    const int l0 = (nt & 1) << 8;
    const short* xbs = (const short*)xbg + (b * XBP + l0) * XBC;   // row i <-> l = l0 + i - 3
    const short* wbp = (const short*)Wbg + wbase;

    floatx16 acc[4][2];
#pragma unroll
    for (int i = 0; i < 4; i++)
#pragma unroll
        for (int j = 0; j < 2; j++)
#pragma unroll
            for (int r = 0; r < 16; r++) acc[i][j][r] = 0.f;

    for (int c5 = 0; c5 < 5; ++c5) {
        const int c0 = c5 * 64;
        __syncthreads();
        for (int j = tid; j < 2096; j += 256) {          // 262 rows x 8 vec8
            int row = j >> 3, ch = (j & 7) << 3;
            *(short8*)&xs[row * LDST + ch] = *(const short8*)&xbs[row * XBC + c0 + ch];
        }
        for (int t = 0; t < taps; ++t) {
            if (t) __syncthreads();
            for (int j = tid; j < 1024; j += 256) {      // 128 rows x 8 vec8
                int row = j >> 3, ch = (j & 7) << 3;
                *(short8*)&wl[row * LDST + ch] =
                    *(const short8*)&wbp[(m0 + row) * pm + t * 320 + c0 + ch];
            }
            __syncthreads();
            const int sh = t - lead + 3;                 // 0..6, xs row shift
            const int abase = (wn * 128 + lr + sh) * LDST + lk;
            const int bbase = (wm * 64 + lr) * LDST + lk;
#pragma unroll
            for (int ks = 0; ks < 4; ++ks) {
                const int ko = ks * 16;
                short8 a0 = *(const short8*)&xs[abase + ko];
                short8 a1 = *(const short8*)&xs[abase + 32 * LDST + ko];
                short8 a2 = *(const short8*)&xs[abase + 64 * LDST + ko];
                short8 a3 = *(const short8*)&xs[abase + 96 * LDST + ko];
                short8 b0 = *(const short8*)&wl[bbase + ko];
                short8 b1 = *(const short8*)&wl[bbase + 32 * LDST + ko];
                acc[0][0] = MFMA(a0, b0, acc[0][0], 0, 0, 0);
                acc[0][1] = MFMA(a0, b1, acc[0][1], 0, 0, 0);
                acc[1][0] = MFMA(a1, b0, acc[1][0], 0, 0, 0);
                acc[1][1] = MFMA(a1, b1, acc[1][1], 0, 0, 0);
                acc[2][0] = MFMA(a2, b0, acc[2][0], 0, 0, 0);
                acc[2][1] = MFMA(a2, b1, acc[2][1], 0, 0, 0);
                acc[3][0] = MFMA(a3, b0, acc[3][0], 0, 0, 0);
                acc[3][1] = MFMA(a3, b1, acc[3][1], 0, 0, 0);
            }
        }
    }

    const float* bias = (cid == 0) ? bias1 : (cid == 1) ? bias2 : (cid == 2) ? bias3 : bias7;
#pragma unroll
    for (int mi = 0; mi < 2; ++mi) {
        int mloc = m0 + wm * 64 + mi * 32 + lr;
        if (mloc < Cn) {
            float bv = bias[mloc];
            int col = cid * Cn + mloc;
#pragma unroll
            for (int ni = 0; ni < 4; ++ni) {
                floatx16 v = acc[ni][mi];
#pragma unroll
                for (int reg = 0; reg < 16; ++reg) {
                    int nl = wn * 128 + ni * 32 + (reg & 3) + ((reg >> 2) << 3) + ((lane >> 5) << 2);
                    int n = nt * 256 + nl;
                    hbuf[n * HK + col] = __float2bfloat16(tanhf(v[reg] + bv));
                }
            }
        }
    }
}

// ---------------- linear GEMM ----------------
// grid (64 n-tiles, 4 h-tiles), block 256; block tile 256n x 128m; BK=64; K = 1216
__global__ __launch_bounds__(256, 2) void linear_kernel(
        const __hip_bfloat16* __restrict__ hbufg, const __hip_bfloat16* __restrict__ Wcg,
        const float* __restrict__ slp_b, float* __restrict__ out) {
    __shared__ __align__(16) short hs[256 * LDST];   // 36,864 B
    __shared__ __align__(16) short wl[128 * LDST];   // 18,432 B

    const int tid  = threadIdx.x;
    const int lane = tid & 63;
    const int wave = tid >> 6;
    const int wn = wave & 1, wm = wave >> 1;
    const int lr = lane & 31;
    const int lk = (lane >> 5) * 8;

    const int nt = blockIdx.x;
    const int m0 = blockIdx.y * 128;

    const short* hb = (const short*)hbufg + nt * 256 * HK;
    const short* wc = (const short*)Wcg + m0 * HK;

    floatx16 acc[4][2];
#pragma unroll
    for (int i = 0; i < 4; i++)
#pragma unroll
        for (int j = 0; j < 2; j++)
#pragma unroll
            for (int r = 0; r < 16; r++) acc[i][j][r] = 0.f;

    for (int chunk = 0; chunk < 19; ++chunk) {
        const int c0 = chunk * 64;
        __syncthreads();
        for (int j = tid; j < 2048; j += 256) {          // 256 rows x 8 vec8
            int row = j >> 3, ch = (j & 7) << 3;
            *(short8*)&hs[row * LDST + ch] = *(const short8*)&hb[row * HK + c0 + ch];
        }
        for (int j = tid; j < 1024; j += 256) {          // 128 rows x 8 vec8
            int row = j >> 3, ch = (j & 7) << 3;
            *(short8*)&wl[row * LDST + ch] = *(const short8*)&wc[row * HK + c0 + ch];
        }
        __syncthreads();
        const int abase = (wn * 128 + lr) * LDST + lk;
        const int bbase = (wm * 64 + lr) * LDST + lk;
#pragma unroll
        for (int ks = 0; ks < 4; ++ks) {
            const int ko = ks * 16;
            short8 a0 = *(const short8*)&hs[abase + ko];
            short8 a1 = *(const short8*)&hs[abase + 32 * LDST + ko];
            short8 a2 = *(const short8*)&hs[abase + 64 * LDST + ko];
            short8 a3 = *(const short8*)&hs[abase + 96 * LDST + ko];
            short8 b0 = *(const short8*)&wl[bbase + ko];
            short8 b1 = *(const short8*)&wl[bbase + 32 * LDST + ko];
            acc[0][0] = MFMA(a0, b0, acc[0][0], 0, 0, 0);
            acc[0][1] = MFMA(a0, b1, acc[0][1], 0, 0, 0);
            acc[1][0] = MFMA(a1, b0, acc[1][0], 0, 0, 0);
            acc[1][1] = MFMA(a1, b1, acc[1][1], 0, 0, 0);
            acc[2][0] = MFMA(a2, b0, acc[2][0], 0, 0, 0);
            acc[2][1] = MFMA(a2, b1, acc[2][1], 0, 0, 0);
            acc[3][0] = MFMA(a3, b0, acc[3][0], 0, 0, 0);
            acc[3][1] = MFMA(a3, b1, acc[3][1], 0, 0, 0);
        }
    }

#pragma unroll
    for (int mi = 0; mi < 2; ++mi) {
        int h = m0 + wm * 64 + mi * 32 + lr;
        float bv = slp_b[h];
#pragma unroll
        for (int ni = 0; ni < 4; ++ni) {
            floatx16 v = acc[ni][mi];
#pragma unroll
            for (int reg = 0; reg < 16; ++reg) {
                int nl = wn * 128 + ni * 32 + (reg & 3) + ((reg >> 2) << 3) + ((lane >> 5) << 2);
                int n = nt * 256 + nl;
                out[n * Hn + h] = tanhf(v[reg] + bv);
            }
        }
    }
}

// ---------------- launch ----------------

extern "C" void kernel_launch(void* const* d_in, const int* in_sizes, int n_in,
                              void* d_out, int out_size, void* d_ws, size_t ws_size,
                              hipStream_t stream) {
    const float* x     = (const float*)d_in[0];
    const float* w1    = (const float*)d_in[1];
    const float* b1    = (const float*)d_in[2];
    const float* w2    = (const float*)d_in[3];
    const float* b2    = (const float*)d_in[4];
    const float* w3    = (const float*)d_in[5];
    const float* b3    = (const float*)d_in[6];
    const float* w7    = (const float*)d_in[7];
    const float* b7    = (const float*)d_in[8];
    const float* slp_w = (const float*)d_in[9];
    const float* slp_b = (const float*)d_in[10];

    __hip_bfloat16* wsb = (__hip_bfloat16*)d_ws;

    prep_x<<<(XB_ELEMS + 255) / 256, 256, 0, stream>>>(x, wsb + XB_OFF);
    prep_w<<<(WB_ELEMS + 255) / 256, 256, 0, stream>>>(w1, w2, w3, w7, wsb + WB_OFF);
    prep_wc<<<(WC_ELEMS + 255) / 256, 256, 0, stream>>>(slp_w, wsb + WC_OFF);

    conv_kernel<<<dim3(64, 12), 256, 0, stream>>>(wsb + XB_OFF, wsb + WB_OFF,
                                                  b1, b2, b3, b7, wsb + HB_OFF);
    linear_kernel<<<dim3(64, 4), 256, 0, stream>>>(wsb + HB_OFF, wsb + WC_OFF,
                                                   slp_b, (float*)d_out);
}

// Round 3
// 201.780 us; speedup vs baseline: 1.4193x; 1.4193x over previous
//
#include <hip/hip_runtime.h>
#include <hip/hip_bf16.h>

typedef __attribute__((ext_vector_type(8))) short short8;
typedef __attribute__((ext_vector_type(16))) float floatx16;

#define Bn 32
#define Ln 512
#define Cn 300
#define Hn 512
#define Nn (Bn*Ln)          // 16384
#define XBP 518             // 512 + 3 halo each side
#define XBC 320             // channels padded to 10*32
#define HK 1216             // 1200 padded to 19*64
#define LDST 72             // LDS row stride in shorts (conflict-free b128, verified r2)

#define XSROWS 262
#define XSSZ (XSROWS*LDST)  // 18864 shorts = 37728 B (x2 buffers = 75456 B)
#define HSROWS 128
#define HSSZ (HSROWS*LDST)  // 9216 shorts = 18432 B (x2 = 36864 B)

// workspace layout in bf16 elements
#define XB_OFF 0
#define XB_ELEMS (Bn*XBP*XBC)           // 5,304,320
#define WB_OFF (XB_OFF + XB_ELEMS)
#define WB_ELEMS 1597440                 // sum over convs of 122880*taps
#define WC_OFF (WB_OFF + WB_ELEMS)
#define WC_ELEMS (Hn*HK)                 // 622,592
#define HB_OFF (WC_OFF + WC_ELEMS)
#define HB_ELEMS (Nn*HK)

__device__ __forceinline__ float fast_tanh(float x) {
    float ax = __builtin_fabsf(x);
    float t  = __expf(-2.f * ax);
    float r  = __builtin_fmaf(-2.f * t, __frcp_rn(1.f + t), 1.f);  // (1-t)/(1+t)
    return __builtin_copysignf(r, x);
}

// ---------------- prep kernels ----------------

__global__ void prep_x(const float* __restrict__ x, __hip_bfloat16* __restrict__ xb) {
    int idx = blockIdx.x * 256 + threadIdx.x;
    if (idx >= Bn * XBP * XBC) return;
    int c = idx % XBC;
    int t = idx / XBC;
    int p = t % XBP;
    int b = t / XBP;
    int l = p - 3;
    l = l < 0 ? 0 : (l > Ln - 1 ? Ln - 1 : l);   // replication pad
    float v = (c < Cn) ? x[(b * Ln + l) * Cn + c] : 0.f;
    xb[idx] = __float2bfloat16(v);
}

// Frag-major weights. Per conv: idx = ((((mt*5+ch)*taps + t)*16 + ks*4+mq)*512 + lane*8 + e
// value = W[m = mt*128 + mq*32 + (lane&31)][c = ch*64 + ks*16 + (lane>>5)*8 + e][tap t]
__global__ void prep_w(const float* __restrict__ w1, const float* __restrict__ w2,
                       const float* __restrict__ w3, const float* __restrict__ w7,
                       __hip_bfloat16* __restrict__ Wb) {
    int idx = blockIdx.x * 256 + threadIdx.x;
    if (idx >= WB_ELEMS) return;
    int r = idx, taps; const float* w;
    if (r < 122880)       { taps = 1; w = w1; }
    else if (r < 368640)  { taps = 2; w = w2; r -= 122880; }
    else if (r < 737280)  { taps = 3; w = w3; r -= 368640; }
    else                  { taps = 7; w = w7; r -= 737280; }
    int e    = r & 7;
    int lane = (r >> 3) & 63;
    int f    = (r >> 9) & 15;
    int rt   = r >> 13;              // (mt*5+ch)*taps + t
    int t    = rt % taps;
    int mc   = rt / taps;
    int ch   = mc % 5;
    int mt   = mc / 5;
    int ks = f >> 2, mq = f & 3;
    int m = mt * 128 + mq * 32 + (lane & 31);
    int c = ch * 64 + ks * 16 + (lane >> 5) * 8 + e;
    float v = (m < Cn && c < Cn) ? w[(m * Cn + c) * taps + t] : 0.f;
    Wb[idx] = __float2bfloat16(v);
}

// Frag-major combined linear weight (x3/x5 columns folded):
// idx = ((mt4*19 + ch)*16 + ks*4+mq)*512 + lane*8 + e
// h = mt4*128 + mq*32 + (lane&31); k = ch*64 + ks*16 + (lane>>5)*8 + e
__global__ void prep_wc(const float* __restrict__ slp_w, __hip_bfloat16* __restrict__ Wc) {
    int idx = blockIdx.x * 256 + threadIdx.x;
    if (idx >= Hn * HK) return;
    int e    = idx & 7;
    int lane = (idx >> 3) & 63;
    int f    = (idx >> 9) & 15;
    int mc   = idx >> 13;
    int ch   = mc % 19;
    int mt4  = mc / 19;
    int ks = f >> 2, mq = f & 3;
    int h = mt4 * 128 + mq * 32 + (lane & 31);
    int k = ch * 64 + ks * 16 + (lane >> 5) * 8 + e;
    const float* row = slp_w + h * 1500;
    float v;
    if (k < 600)       v = row[k];
    else if (k < 900)  v = row[k] + row[k + 300];
    else if (k < 1200) v = row[k + 300];
    else               v = 0.f;
    Wc[idx] = __float2bfloat16(v);
}

#define MFMA __builtin_amdgcn_mfma_f32_32x32x16_bf16

// ---------------- conv GEMM ----------------
// grid (64 n-tiles of 256, 12 m-tiles; heavy convs first), block 256 = 4 waves
// block tile 256n x 128m; wave tile 128n x 64m (4x2); BK=64; B-frags direct from global;
// x double-buffered in LDS -> ONE barrier per k-chunk, taps loop barrier-free.
__global__ __launch_bounds__(256, 2) void conv_kernel(
        const __hip_bfloat16* __restrict__ xbg, const __hip_bfloat16* __restrict__ Wbg,
        const float* __restrict__ bias1, const float* __restrict__ bias2,
        const float* __restrict__ bias3, const float* __restrict__ bias7,
        __hip_bfloat16* __restrict__ hbuf) {
    __shared__ __align__(16) short xs[2 * XSSZ];

    const int tid  = threadIdx.x;
    const int lane = tid & 63;
    const int wave = tid >> 6;
    const int wn = wave & 1, wm = wave >> 1;
    const int lr = lane & 31;
    const int lk = (lane >> 5) << 3;

    const int nt  = blockIdx.x;
    const int my  = blockIdx.y;
    const int cid = 3 - my / 3;              // heavy (k=7) first
    const int mt  = my % 3;

    const int taps  = (cid == 0) ? 1 : (cid == 1) ? 2 : (cid == 2) ? 3 : 7;
    const int lead  = (cid == 2) ? 1 : (cid == 3) ? 3 : 0;
    const int fbase = (cid == 0) ? 0 : (cid == 1) ? 122880 : (cid == 2) ? 368640 : 737280;

    const int b  = nt >> 1;
    const int l0 = (nt & 1) << 8;
    const short* xbs = (const short*)xbg + (b * XBP + l0) * XBC;   // row i <-> l = l0 + i - 3
    const short* wsp = (const short*)Wbg + fbase + mt * taps * 40960;

    const int srow = tid >> 3;               // 0..31
    const int scc  = (tid & 7) << 3;         // 0..56

    floatx16 acc[4][2];
#pragma unroll
    for (int i = 0; i < 4; i++)
#pragma unroll
        for (int j = 0; j < 2; j++)
#pragma unroll
            for (int r = 0; r < 16; r++) acc[i][j][r] = 0.f;

    // prologue: stage chunk 0 into xs[0]
#pragma unroll
    for (int i = 0; i < 9; ++i) {
        int row = srow + 32 * i;
        if (i < 8 || row < XSROWS)
            *(short8*)&xs[row * LDST + scc] = *(const short8*)&xbs[row * XBC + scc];
    }
    __syncthreads();

    for (int c5 = 0; c5 < 5; ++c5) {
        const short* cur = xs + (c5 & 1) * XSSZ;
        short8 st[9];
        if (c5 < 4) {                                    // issue next chunk's loads early
            const int c0n = (c5 + 1) * 64;
#pragma unroll
            for (int i = 0; i < 9; ++i) {
                int row = srow + 32 * i;
                if (i < 8 || row < XSROWS)
                    st[i] = *(const short8*)&xbs[row * XBC + c0n + scc];
            }
        }
        for (int t = 0; t < taps; ++t) {                 // barrier-free straight line
            const short* wt = wsp + (c5 * taps + t) * 8192;
            const int ab = (wn * 128 + lr + (t - lead + 3)) * LDST + lk;
#pragma unroll
            for (int ks = 0; ks < 4; ++ks) {
                short8 bf0 = *(const short8*)&wt[(ks * 4 + wm * 2 + 0) * 512 + lane * 8];
                short8 bf1 = *(const short8*)&wt[(ks * 4 + wm * 2 + 1) * 512 + lane * 8];
                const int ko = ks * 16;
                short8 a0 = *(const short8*)&cur[ab + ko];
                short8 a1 = *(const short8*)&cur[ab + 32 * LDST + ko];
                short8 a2 = *(const short8*)&cur[ab + 64 * LDST + ko];
                short8 a3 = *(const short8*)&cur[ab + 96 * LDST + ko];
                acc[0][0] = MFMA(a0, bf0, acc[0][0], 0, 0, 0);
                acc[0][1] = MFMA(a0, bf1, acc[0][1], 0, 0, 0);
                acc[1][0] = MFMA(a1, bf0, acc[1][0], 0, 0, 0);
                acc[1][1] = MFMA(a1, bf1, acc[1][1], 0, 0, 0);
                acc[2][0] = MFMA(a2, bf0, acc[2][0], 0, 0, 0);
                acc[2][1] = MFMA(a2, bf1, acc[2][1], 0, 0, 0);
                acc[3][0] = MFMA(a3, bf0, acc[3][0], 0, 0, 0);
                acc[3][1] = MFMA(a3, bf1, acc[3][1], 0, 0, 0);
            }
        }
        if (c5 < 4) {                                    // land staged data in other buffer
            short* nxt = xs + ((c5 + 1) & 1) * XSSZ;
#pragma unroll
            for (int i = 0; i < 9; ++i) {
                int row = srow + 32 * i;
                if (i < 8 || row < XSROWS)
                    *(short8*)&nxt[row * LDST + scc] = st[i];
            }
        }
        __syncthreads();
    }

    const float* bias = (cid == 0) ? bias1 : (cid == 1) ? bias2 : (cid == 2) ? bias3 : bias7;
#pragma unroll
    for (int mi = 0; mi < 2; ++mi) {
        int mloc = mt * 128 + wm * 64 + mi * 32 + lr;
        if (mloc < Cn) {
            float bv = bias[mloc];
            int col = cid * Cn + mloc;
#pragma unroll
            for (int ni = 0; ni < 4; ++ni) {
                floatx16 v = acc[ni][mi];
#pragma unroll
                for (int reg = 0; reg < 16; ++reg) {
                    int nl = wn * 128 + ni * 32 + (reg & 3) + ((reg >> 2) << 3) + ((lane >> 5) << 2);
                    int n = nt * 256 + nl;
                    hbuf[n * HK + col] = __float2bfloat16(fast_tanh(v[reg] + bv));
                }
            }
        }
    }
}

// ---------------- linear GEMM ----------------
// grid (128 n-tiles of 128, 4 h-tiles), block 256; block tile 128n x 128m;
// wave tile 64x64 (2x2); B-frags direct from global; h double-buffered in LDS.
__global__ __launch_bounds__(256, 3) void linear_kernel(
        const __hip_bfloat16* __restrict__ hbufg, const __hip_bfloat16* __restrict__ Wcg,
        const float* __restrict__ slp_b, float* __restrict__ out) {
    __shared__ __align__(16) short hs[2 * HSSZ];

    const int tid  = threadIdx.x;
    const int lane = tid & 63;
    const int wave = tid >> 6;
    const int wn = wave & 1, wm = wave >> 1;
    const int lr = lane & 31;
    const int lk = (lane >> 5) << 3;

    const int nt  = blockIdx.x;
    const int mt4 = blockIdx.y;

    const short* hbp = (const short*)hbufg + nt * 128 * HK;
    const short* wcp = (const short*)Wcg + mt4 * 155648;   // 19*16*512

    const int srow = tid >> 3;
    const int scc  = (tid & 7) << 3;

    floatx16 acc[2][2];
#pragma unroll
    for (int i = 0; i < 2; i++)
#pragma unroll
        for (int j = 0; j < 2; j++)
#pragma unroll
            for (int r = 0; r < 16; r++) acc[i][j][r] = 0.f;

    // prologue: stage chunk 0
#pragma unroll
    for (int i = 0; i < 4; ++i) {
        int row = srow + 32 * i;
        *(short8*)&hs[row * LDST + scc] = *(const short8*)&hbp[row * HK + scc];
    }
    __syncthreads();

    for (int ch = 0; ch < 19; ++ch) {
        const short* cur = hs + (ch & 1) * HSSZ;
        short8 st[4];
        if (ch < 18) {
            const int c0n = (ch + 1) * 64;
#pragma unroll
            for (int i = 0; i < 4; ++i) {
                int row = srow + 32 * i;
                st[i] = *(const short8*)&hbp[row * HK + c0n + scc];
            }
        }
        const short* wt = wcp + ch * 8192;
        const int ab = (wn * 64 + lr) * LDST + lk;
#pragma unroll
        for (int ks = 0; ks < 4; ++ks) {
            short8 bf0 = *(const short8*)&wt[(ks * 4 + wm * 2 + 0) * 512 + lane * 8];
            short8 bf1 = *(const short8*)&wt[(ks * 4 + wm * 2 + 1) * 512 + lane * 8];
            const int ko = ks * 16;
            short8 a0 = *(const short8*)&cur[ab + ko];
            short8 a1 = *(const short8*)&cur[ab + 32 * LDST + ko];
            acc[0][0] = MFMA(a0, bf0, acc[0][0], 0, 0, 0);
            acc[0][1] = MFMA(a0, bf1, acc[0][1], 0, 0, 0);
            acc[1][0] = MFMA(a1, bf0, acc[1][0], 0, 0, 0);
            acc[1][1] = MFMA(a1, bf1, acc[1][1], 0, 0, 0);
        }
        if (ch < 18) {
            short* nxt = hs + ((ch + 1) & 1) * HSSZ;
#pragma unroll
            for (int i = 0; i < 4; ++i) {
                int row = srow + 32 * i;
                *(short8*)&nxt[row * LDST + scc] = st[i];
            }
        }
        __syncthreads();
    }

#pragma unroll
    for (int mi = 0; mi < 2; ++mi) {
        int h = mt4 * 128 + wm * 64 + mi * 32 + lr;
        float bv = slp_b[h];
#pragma unroll
        for (int ni = 0; ni < 2; ++ni) {
            floatx16 v = acc[ni][mi];
#pragma unroll
            for (int reg = 0; reg < 16; ++reg) {
                int nl = wn * 64 + ni * 32 + (reg & 3) + ((reg >> 2) << 3) + ((lane >> 5) << 2);
                int n = nt * 128 + nl;
                out[n * Hn + h] = fast_tanh(v[reg] + bv);
            }
        }
    }
}

// ---------------- launch ----------------

extern "C" void kernel_launch(void* const* d_in, const int* in_sizes, int n_in,
                              void* d_out, int out_size, void* d_ws, size_t ws_size,
                              hipStream_t stream) {
    const float* x     = (const float*)d_in[0];
    const float* w1    = (const float*)d_in[1];
    const float* b1    = (const float*)d_in[2];
    const float* w2    = (const float*)d_in[3];
    const float* b2    = (const float*)d_in[4];
    const float* w3    = (const float*)d_in[5];
    const float* b3    = (const float*)d_in[6];
    const float* w7    = (const float*)d_in[7];
    const float* b7    = (const float*)d_in[8];
    const float* slp_w = (const float*)d_in[9];
    const float* slp_b = (const float*)d_in[10];

    __hip_bfloat16* wsb = (__hip_bfloat16*)d_ws;

    prep_x<<<(XB_ELEMS + 255) / 256, 256, 0, stream>>>(x, wsb + XB_OFF);
    prep_w<<<(WB_ELEMS + 255) / 256, 256, 0, stream>>>(w1, w2, w3, w7, wsb + WB_OFF);
    prep_wc<<<(WC_ELEMS + 255) / 256, 256, 0, stream>>>(slp_w, wsb + WC_OFF);

    conv_kernel<<<dim3(64, 12), 256, 0, stream>>>(wsb + XB_OFF, wsb + WB_OFF,
                                                  b1, b2, b3, b7, wsb + HB_OFF);
    linear_kernel<<<dim3(128, 4), 256, 0, stream>>>(wsb + HB_OFF, wsb + WC_OFF,
                                                    slp_b, (float*)d_out);
}

// Round 4
// 187.339 us; speedup vs baseline: 1.5287x; 1.0771x over previous
//
#include <hip/hip_runtime.h>
#include <hip/hip_bf16.h>

typedef __attribute__((ext_vector_type(8))) short short8;
typedef __attribute__((ext_vector_type(16))) float floatx16;

#define Bn 32
#define Ln 512
#define Cn 300
#define Hn 512
#define Nn (Bn*Ln)          // 16384
#define XBP 518             // 512 + 3 halo each side
#define XBC 320             // channels padded to 10*32
#define HK 1216             // 1200 padded to 19*64
#define LDSTC 72            // LDS row stride in shorts (conflict-free b128, verified r2/r3)

#define XROWS 134
#define XSZ (XROWS*LDSTC)   // 9648 shorts = 19296 B (x2 = 38.6 KB)
#define HSROWS 128
#define HSSZ (HSROWS*LDSTC) // 9216 shorts (x2 = 36.9 KB)

// workspace layout in bf16 elements
#define XB_ELEMS (Bn*XBP*XBC)            // 5,304,320
#define WB_ELEMS 1597440                  // (1+2+3+7)*122880, frag-major
#define WC_ELEMS (Hn*HK)                  // 622,592
#define XB_OFF 0
#define WB_OFF (XB_OFF + XB_ELEMS)
#define WC_OFF (WB_OFF + WB_ELEMS)
#define HB_OFF (WC_OFF + WC_ELEMS)

__device__ __forceinline__ float fast_tanh(float x) {
    float ax = __builtin_fabsf(x);
    float t  = __expf(-2.f * ax);
    float r  = __builtin_fmaf(-2.f * t, __frcp_rn(1.f + t), 1.f);  // (1-t)/(1+t)
    return __builtin_copysignf(r, x);
}

// ---------------- merged prep kernel ----------------
// section 1: edge-padded bf16 x   [b][p][c] (XBC-padded channels)
// section 2: frag-major conv weights: per conv, idx=(((mt*5+ch)*taps+t)*16+ks*4+mq)*512+lane*8+e
// section 3: frag-major combined linear weight (x3/x5 folded)
__global__ void prep_all(const float* __restrict__ x,
                         const float* __restrict__ w1, const float* __restrict__ w2,
                         const float* __restrict__ w3, const float* __restrict__ w7,
                         const float* __restrict__ slp_w,
                         __hip_bfloat16* __restrict__ wsb) {
    int idx = blockIdx.x * 256 + threadIdx.x;
    if (idx < XB_ELEMS) {
        int c = idx % XBC;
        int t = idx / XBC;
        int p = t % XBP;
        int b = t / XBP;
        int l = p - 3;
        l = l < 0 ? 0 : (l > Ln - 1 ? Ln - 1 : l);   // replication pad
        float v = (c < Cn) ? x[(b * Ln + l) * Cn + c] : 0.f;
        wsb[idx] = __float2bfloat16(v);
    } else if (idx < WB_OFF + WB_ELEMS) {
        int r = idx - WB_OFF, taps; const float* w;
        if (r < 122880)       { taps = 1; w = w1; }
        else if (r < 368640)  { taps = 2; w = w2; r -= 122880; }
        else if (r < 737280)  { taps = 3; w = w3; r -= 368640; }
        else                  { taps = 7; w = w7; r -= 737280; }
        int e    = r & 7;
        int lane = (r >> 3) & 63;
        int f    = (r >> 9) & 15;
        int rt   = r >> 13;              // (mt*5+ch)*taps + t
        int t    = rt % taps;
        int mc   = rt / taps;
        int ch   = mc % 5;
        int mt   = mc / 5;
        int ks = f >> 2, mq = f & 3;
        int m = mt * 128 + mq * 32 + (lane & 31);
        int c = ch * 64 + ks * 16 + (lane >> 5) * 8 + e;
        float v = (m < Cn && c < Cn) ? w[(m * Cn + c) * taps + t] : 0.f;
        wsb[idx] = __float2bfloat16(v);
    } else if (idx < WC_OFF + WC_ELEMS) {
        int r = idx - WC_OFF;
        int e    = r & 7;
        int lane = (r >> 3) & 63;
        int f    = (r >> 9) & 15;
        int mc   = r >> 13;
        int ch   = mc % 19;
        int mt4  = mc / 19;
        int ks = f >> 2, mq = f & 3;
        int h = mt4 * 128 + mq * 32 + (lane & 31);
        int k = ch * 64 + ks * 16 + (lane >> 5) * 8 + e;
        const float* row = slp_w + h * 1500;
        float v;
        if (k < 600)       v = row[k];
        else if (k < 900)  v = row[k] + row[k + 300];
        else if (k < 1200) v = row[k + 300];
        else               v = 0.f;
        wsb[idx] = __float2bfloat16(v);
    }
}

#define MFMA __builtin_amdgcn_mfma_f32_32x32x16_bf16

// ---------------- conv GEMM body ----------------
// block tile 128n x 128m, 4 waves, wave tile 64n x 64m (acc 2x2 = 64 AGPR)
// B-frags direct from global, register double-buffered one stage ahead.
// x double-buffered in LDS; staging loads issued at stage TAPS-2 so they sit
// BEHIND all b-frags consumed this chunk in the vmcnt queue.
template<int TAPS, int LEAD>
__device__ __forceinline__ void conv_body(
        const short* __restrict__ xbs, const short* __restrict__ wsp,
        const float* __restrict__ bias, int cid, int mt, int nt,
        __hip_bfloat16* __restrict__ hbuf, short* xs) {
    const int tid  = threadIdx.x;
    const int lane = tid & 63;
    const int wave = tid >> 6;
    const int wn = wave & 1, wm = wave >> 1;
    const int lr = lane & 31;
    const int lk = (lane >> 5) << 3;
    const int TRIG = (TAPS >= 3) ? TAPS - 2 : 0;

    floatx16 acc[2][2];
#pragma unroll
    for (int i = 0; i < 2; i++)
#pragma unroll
        for (int j = 0; j < 2; j++)
#pragma unroll
            for (int r = 0; r < 16; r++) acc[i][j][r] = 0.f;

    short8 bA[8], bB[8], st[5];

    // prologue: stage chunk 0 + preload stage(0,0) b-frags
#pragma unroll
    for (int i = 0; i < 5; ++i) {
        int j = tid + 256 * i;
        if (i < 4 || j < 1072)
            st[i] = *(const short8*)&xbs[(j >> 3) * XBC + ((j & 7) << 3)];
    }
#pragma unroll
    for (int ks = 0; ks < 4; ++ks)
#pragma unroll
        for (int mf = 0; mf < 2; ++mf)
            bA[ks * 2 + mf] = *(const short8*)&wsp[(ks * 4 + wm * 2 + mf) * 512 + lane * 8];
#pragma unroll
    for (int i = 0; i < 5; ++i) {
        int j = tid + 256 * i;
        if (i < 4 || j < 1072)
            *(short8*)&xs[(j >> 3) * LDSTC + ((j & 7) << 3)] = st[i];
    }
    __syncthreads();

    for (int c5 = 0; c5 < 5; ++c5) {
        const short* cur = xs + (c5 & 1) * XSZ;
        short* nxt = xs + ((c5 + 1) & 1) * XSZ;
        const int c0n = (c5 + 1) * 64;
#pragma unroll
        for (int t = 0; t < TAPS; ++t) {
            // prefetch next stage's B fragments (older than any staging issued later)
            if (!(c5 == 4 && t == TAPS - 1)) {
                const short* wtn = (t + 1 < TAPS) ? wsp + (c5 * TAPS + t + 1) * 8192
                                                  : wsp + ((c5 + 1) * TAPS) * 8192;
#pragma unroll
                for (int ks = 0; ks < 4; ++ks)
#pragma unroll
                    for (int mf = 0; mf < 2; ++mf)
                        bB[ks * 2 + mf] = *(const short8*)&wtn[(ks * 4 + wm * 2 + mf) * 512 + lane * 8];
            }
            if (t == TRIG && c5 < 4) {           // staging: issued after this chunk's b-frags
#pragma unroll
                for (int i = 0; i < 5; ++i) {
                    int j = tid + 256 * i;
                    if (i < 4 || j < 1072)
                        st[i] = *(const short8*)&xbs[(j >> 3) * XBC + c0n + ((j & 7) << 3)];
                }
            }
            const int sh = t - LEAD + 3;
            const int ar = (wn * 64 + lr + sh) * LDSTC + lk;
#pragma unroll
            for (int ks = 0; ks < 4; ++ks) {
                short8 a0 = *(const short8*)&cur[ar + ks * 16];
                short8 a1 = *(const short8*)&cur[ar + 32 * LDSTC + ks * 16];
                acc[0][0] = MFMA(a0, bA[ks * 2 + 0], acc[0][0], 0, 0, 0);
                acc[0][1] = MFMA(a0, bA[ks * 2 + 1], acc[0][1], 0, 0, 0);
                acc[1][0] = MFMA(a1, bA[ks * 2 + 0], acc[1][0], 0, 0, 0);
                acc[1][1] = MFMA(a1, bA[ks * 2 + 1], acc[1][1], 0, 0, 0);
            }
            if (!(c5 == 4 && t == TAPS - 1)) {
#pragma unroll
                for (int f = 0; f < 8; ++f) bA[f] = bB[f];
            }
        }
        if (c5 < 4) {
#pragma unroll
            for (int i = 0; i < 5; ++i) {
                int j = tid + 256 * i;
                if (i < 4 || j < 1072)
                    *(short8*)&nxt[(j >> 3) * LDSTC + ((j & 7) << 3)] = st[i];
            }
        }
        __syncthreads();
    }

#pragma unroll
    for (int mi = 0; mi < 2; ++mi) {
        int mloc = mt * 128 + wm * 64 + mi * 32 + lr;
        if (mloc < Cn) {
            float bv = bias[mloc];
            int col = cid * Cn + mloc;
#pragma unroll
            for (int ni = 0; ni < 2; ++ni) {
                floatx16 v = acc[ni][mi];
#pragma unroll
                for (int reg = 0; reg < 16; ++reg) {
                    int nl = wn * 64 + ni * 32 + (reg & 3) + ((reg >> 2) << 3) + ((lane >> 5) << 2);
                    int n = nt * 128 + nl;
                    hbuf[n * HK + col] = __float2bfloat16(fast_tanh(v[reg] + bv));
                }
            }
        }
    }
}

// grid (128 n-tiles of 128, 12 y; heavy convs first)
__global__ __launch_bounds__(256, 2) void conv_kernel(
        const __hip_bfloat16* __restrict__ xbg, const __hip_bfloat16* __restrict__ Wbg,
        const float* __restrict__ bias1, const float* __restrict__ bias2,
        const float* __restrict__ bias3, const float* __restrict__ bias7,
        __hip_bfloat16* __restrict__ hbuf) {
    __shared__ __align__(16) short xs[2 * XSZ];

    const int nt = blockIdx.x;
    const int my = blockIdx.y;
    const int g  = my / 3;                   // 0:conv7 1:conv3 2:conv2 3:conv1
    const int mt = my % 3;

    const int b  = nt >> 2;
    const int l0 = (nt & 3) << 7;
    const short* xbs = (const short*)xbg + (b * XBP + l0) * XBC;
    const short* wb  = (const short*)Wbg;

    if (g == 0)      conv_body<7, 3>(xbs, wb + 737280 + mt * 7 * 40960, bias7, 3, mt, nt, hbuf, xs);
    else if (g == 1) conv_body<3, 1>(xbs, wb + 368640 + mt * 3 * 40960, bias3, 2, mt, nt, hbuf, xs);
    else if (g == 2) conv_body<2, 0>(xbs, wb + 122880 + mt * 2 * 40960, bias2, 1, mt, nt, hbuf, xs);
    else             conv_body<1, 0>(xbs, wb +      0 + mt * 1 * 40960, bias1, 0, mt, nt, hbuf, xs);
}

// ---------------- linear GEMM ----------------
// grid (128 n-tiles of 128, 4 h-tiles), block 256; tile 128n x 128m; wave 64x64 acc 2x2;
// B-frags register double-buffered one chunk ahead; staging issued after b-prefetch.
__global__ __launch_bounds__(256, 2) void linear_kernel(
        const __hip_bfloat16* __restrict__ hbufg, const __hip_bfloat16* __restrict__ Wcg,
        const float* __restrict__ slp_b, float* __restrict__ out) {
    __shared__ __align__(16) short hs[2 * HSSZ];

    const int tid  = threadIdx.x;
    const int lane = tid & 63;
    const int wave = tid >> 6;
    const int wn = wave & 1, wm = wave >> 1;
    const int lr = lane & 31;
    const int lk = (lane >> 5) << 3;

    const int nt  = blockIdx.x;
    const int mt4 = blockIdx.y;

    const short* hbp = (const short*)hbufg + nt * 128 * HK;
    const short* wcp = (const short*)Wcg + mt4 * 155648;   // 19*16*512

    const int srow = tid >> 1;               // 0..127
    const int scc  = (tid & 1) << 5;         // 0 or 32 (two 16B... no: 32 shorts)
    // staging: 128 rows x 64 shorts = 1024 short8 groups; j = tid + 256*i, i<4
    floatx16 acc[2][2];
#pragma unroll
    for (int i = 0; i < 2; i++)
#pragma unroll
        for (int j = 0; j < 2; j++)
#pragma unroll
            for (int r = 0; r < 16; r++) acc[i][j][r] = 0.f;

    short8 bA[8], bB[8], st[4];
    (void)srow; (void)scc;

    // prologue: stage chunk 0, preload chunk-0 b-frags
#pragma unroll
    for (int i = 0; i < 4; ++i) {
        int j = tid + 256 * i;
        st[i] = *(const short8*)&hbp[(j >> 3) * HK + ((j & 7) << 3)];
    }
#pragma unroll
    for (int ks = 0; ks < 4; ++ks)
#pragma unroll
        for (int mf = 0; mf < 2; ++mf)
            bA[ks * 2 + mf] = *(const short8*)&wcp[(ks * 4 + wm * 2 + mf) * 512 + lane * 8];
#pragma unroll
    for (int i = 0; i < 4; ++i) {
        int j = tid + 256 * i;
        *(short8*)&hs[(j >> 3) * LDSTC + ((j & 7) << 3)] = st[i];
    }
    __syncthreads();

    for (int ch = 0; ch < 19; ++ch) {
        const short* cur = hs + (ch & 1) * HSSZ;
        short* nxt = hs + ((ch + 1) & 1) * HSSZ;
        if (ch < 18) {
            const short* wtn = wcp + (ch + 1) * 8192;
#pragma unroll
            for (int ks = 0; ks < 4; ++ks)
#pragma unroll
                for (int mf = 0; mf < 2; ++mf)
                    bB[ks * 2 + mf] = *(const short8*)&wtn[(ks * 4 + wm * 2 + mf) * 512 + lane * 8];
            const int c0n = (ch + 1) * 64;
#pragma unroll
            for (int i = 0; i < 4; ++i) {
                int j = tid + 256 * i;
                st[i] = *(const short8*)&hbp[(j >> 3) * HK + c0n + ((j & 7) << 3)];
            }
        }
        const int ar = (wn * 64 + lr) * LDSTC + lk;
#pragma unroll
        for (int ks = 0; ks < 4; ++ks) {
            short8 a0 = *(const short8*)&cur[ar + ks * 16];
            short8 a1 = *(const short8*)&cur[ar + 32 * LDSTC + ks * 16];
            acc[0][0] = MFMA(a0, bA[ks * 2 + 0], acc[0][0], 0, 0, 0);
            acc[0][1] = MFMA(a0, bA[ks * 2 + 1], acc[0][1], 0, 0, 0);
            acc[1][0] = MFMA(a1, bA[ks * 2 + 0], acc[1][0], 0, 0, 0);
            acc[1][1] = MFMA(a1, bA[ks * 2 + 1], acc[1][1], 0, 0, 0);
        }
        if (ch < 18) {
#pragma unroll
            for (int f = 0; f < 8; ++f) bA[f] = bB[f];
#pragma unroll
            for (int i = 0; i < 4; ++i) {
                int j = tid + 256 * i;
                *(short8*)&nxt[(j >> 3) * LDSTC + ((j & 7) << 3)] = st[i];
            }
        }
        __syncthreads();
    }

#pragma unroll
    for (int mi = 0; mi < 2; ++mi) {
        int h = mt4 * 128 + wm * 64 + mi * 32 + lr;
        float bv = slp_b[h];
#pragma unroll
        for (int ni = 0; ni < 2; ++ni) {
            floatx16 v = acc[ni][mi];
#pragma unroll
            for (int reg = 0; reg < 16; ++reg) {
                int nl = wn * 64 + ni * 32 + (reg & 3) + ((reg >> 2) << 3) + ((lane >> 5) << 2);
                int n = nt * 128 + nl;
                out[n * Hn + h] = fast_tanh(v[reg] + bv);
            }
        }
    }
}

// ---------------- launch ----------------

extern "C" void kernel_launch(void* const* d_in, const int* in_sizes, int n_in,
                              void* d_out, int out_size, void* d_ws, size_t ws_size,
                              hipStream_t stream) {
    const float* x     = (const float*)d_in[0];
    const float* w1    = (const float*)d_in[1];
    const float* b1    = (const float*)d_in[2];
    const float* w2    = (const float*)d_in[3];
    const float* b2    = (const float*)d_in[4];
    const float* w3    = (const float*)d_in[5];
    const float* b3    = (const float*)d_in[6];
    const float* w7    = (const float*)d_in[7];
    const float* b7    = (const float*)d_in[8];
    const float* slp_w = (const float*)d_in[9];
    const float* slp_b = (const float*)d_in[10];

    __hip_bfloat16* wsb = (__hip_bfloat16*)d_ws;

    const int prep_total = XB_ELEMS + WB_ELEMS + WC_ELEMS;   // 7,524,352
    prep_all<<<(prep_total + 255) / 256, 256, 0, stream>>>(x, w1, w2, w3, w7, slp_w, wsb);

    conv_kernel<<<dim3(128, 12), 256, 0, stream>>>(wsb + XB_OFF, wsb + WB_OFF,
                                                   b1, b2, b3, b7, wsb + HB_OFF);
    linear_kernel<<<dim3(128, 4), 256, 0, stream>>>(wsb + HB_OFF, wsb + WC_OFF,
                                                    slp_b, (float*)d_out);
}